// Round 11
// baseline (834.659 us; speedup 1.0000x reference)
//
#include <hip/hip_runtime.h>
#include <hip/hip_bf16.h>
#include <math.h>

#define BB   16
#define NN   96
#define DD   128
#define NCLS 10
#define NBLK 512

typedef __attribute__((ext_vector_type(8))) short bf16x8;
typedef __attribute__((ext_vector_type(8))) unsigned short u16x8;
typedef __attribute__((ext_vector_type(4))) float f32x4;

__device__ __forceinline__ float scalar_as_float(int v) {
    if (v >= -1000000 && v <= 1000000) return (float)v;
    return __int_as_float(v);
}
__device__ __forceinline__ unsigned short f2bf(float f) {
    unsigned u = __float_as_uint(f);
    return (unsigned short)((u + 0x7FFFu + ((u >> 16) & 1u)) >> 16);
}
__device__ __forceinline__ float bf2f(unsigned short h) {
    return __uint_as_float(((unsigned)h) << 16);
}

#define MFMA(A, B, C) __builtin_amdgcn_mfma_f32_16x16x32_bf16(A, B, C, 0, 0, 0)

// software grid barrier: one counter slot per use; all NBLK blocks are HW-guaranteed
// co-resident (LDS 62.8KB/block caps at 2/CU; grid = 2*256). Slots zeroed by
// hipMemsetAsync each launch (replay-deterministic).
__device__ __forceinline__ void gbar(unsigned* c, int slot) {
    __threadfence();
    __syncthreads();
    if (threadIdx.x == 0) {
        __hip_atomic_fetch_add(c + slot, 1u, __ATOMIC_ACQ_REL, __HIP_MEMORY_SCOPE_AGENT);
        while (__hip_atomic_load(c + slot, __ATOMIC_ACQUIRE, __HIP_MEMORY_SCOPE_AGENT) < NBLK)
            __builtin_amdgcn_s_sleep(1);
        __threadfence();
    }
    __syncthreads();
}

// ---- single persistent kernel: prologue (w2 pack + A gather + init) + 5 rounds ----
// Block bx = (b, is) owns rows {is, is+32, is+64} of batch b, all rounds.
// x lives in register xr (w<6 threads); v = e_proj+b1 lives in LDS; only xj crosses
// blocks (global bf16 ping-pong, grid barrier between rounds).
__global__ __launch_bounds__(512, 4) void k_all(
    const int* __restrict__ tok, const float* __restrict__ A,
    const float* __restrict__ embed_W, const float* __restrict__ W1,
    const float* __restrict__ b1, const float* __restrict__ W2,
    const float* __restrict__ b2, const float* __restrict__ Wo1,
    const float* __restrict__ bo1, const float* __restrict__ Wo2,
    const int* __restrict__ tau_p,
    unsigned short* __restrict__ w2hi, unsigned short* __restrict__ xjA,
    unsigned short* __restrict__ xjB, unsigned* __restrict__ cnt,
    float* __restrict__ out, float* __restrict__ x_all)
{
    const int bx = blockIdx.x;   // 0..511
    const int b  = bx >> 5;      // batch 0..15
    const int is = bx & 31;      // rows is, is+32, is+64
    const int t  = threadIdx.x;  // 0..511
    const int w  = t >> 6;       // wave 0..7
    const int l  = t & 63;
    const int jg  = w >> 2;      // j-group 0..1 (3 j-tiles each)
    const int dg  = w & 3;       // d-group 0..3 (d-tiles dg, dg+4)
    const int jg3 = jg * 3;
    const int u6 = w >> 1;                 // epilogue row unit (valid w<6)
    const int tt = ((w & 1) << 6) | l;     // epilogue feature 0..127
    const int d0 = (t & 15) * 8;           // STAGE d-slice
    const float* W1x = W1 + DD * DD;

    __shared__ __align__(16) unsigned short hs[2][NN * DD];  // 48 KB, XOR-swizzled
    __shared__ float ac3_s[3][NN];
    __shared__ float v_s3[3][DD];          // e_proj + b1, constant across rounds
    __shared__ float agg_part[3][2][DD];
    __shared__ float xn_s[3][DD];
    __shared__ float part_s[4][3][DD];
    __shared__ float wred[2][3][NCLS];

    // ---- prologue ----
    if (t < NN) {    // A-column gather (once, amortized over 5 rounds)
        ac3_s[0][t] = A[(b * NN + t) * NN + is];
        ac3_s[1][t] = A[(b * NN + t) * NN + is + 32];
        ac3_s[2][t] = A[(b * NN + t) * NN + is + 64];
    }
    if (bx < 8 && t < 256) {   // distributed W2 frag pack (dt = bx)
        const int kc = t >> 6, ll = t & 63;
        const int base = ((bx * 4 + kc) * 64 + ll) * 8;
        const int c = bx * 16 + (ll & 15);
#pragma unroll
        for (int e = 0; e < 8; ++e)
            w2hi[base + e] = f2bf(W2[(kc * 32 + (ll >> 4) * 8 + e) * DD + c]);
    }
    if (t < 384) {   // embeddings for 3 rows
        const int u = t >> 7, d = t & 127;
        xn_s[u][d] = embed_W[tok[b * NN + is + 32 * u] * DD + d];
    }
    __syncthreads();
    {   // e @ W1e (batched 3 rows, weight read once)
        const int q = t >> 7, h = t & 127;
        float p0 = 0.f, p1 = 0.f, p2 = 0.f;
#pragma unroll
        for (int kk = 0; kk < 32; ++kk) {
            const int k = q * 32 + kk;
            const float wv = W1[k * DD + h];
            p0 = fmaf(xn_s[0][k], wv, p0);
            p1 = fmaf(xn_s[1][k], wv, p1);
            p2 = fmaf(xn_s[2][k], wv, p2);
        }
        part_s[q][0][h] = p0; part_s[q][1][h] = p1; part_s[q][2][h] = p2;
    }
    __syncthreads();
    float xr = 0.f;                        // x[row][tt], persistent register
    if (w < 6) {
        v_s3[u6][tt] = part_s[0][u6][tt] + part_s[1][u6][tt]
                     + part_s[2][u6][tt] + part_s[3][u6][tt] + b1[tt];
        xr = xn_s[u6][tt];                 // x starts as e
    }
    __syncthreads();
    {   // e @ W1x
        const int q = t >> 7, h = t & 127;
        float p0 = 0.f, p1 = 0.f, p2 = 0.f;
#pragma unroll
        for (int kk = 0; kk < 32; ++kk) {
            const int k = q * 32 + kk;
            const float wv = W1x[k * DD + h];
            p0 = fmaf(xn_s[0][k], wv, p0);
            p1 = fmaf(xn_s[1][k], wv, p1);
            p2 = fmaf(xn_s[2][k], wv, p2);
        }
        part_s[q][0][h] = p0; part_s[q][1][h] = p1; part_s[q][2][h] = p2;
    }
    __syncthreads();
    if (w < 6)
        xjA[(b * NN + is + 32 * u6) * DD + tt] =
            f2bf(part_s[0][u6][tt] + part_s[1][u6][tt]
               + part_s[2][u6][tt] + part_s[3][u6][tt]);
    gbar(cnt, 0);

    // ---- B-fragments once for all rounds, pinned ----
    const bf16x8* WH = (const bf16x8*)w2hi;
    const int f0 = (dg * 4) * 64 + l;
    const int f1 = ((dg + 4) * 4) * 64 + l;
    bf16x8 bh00 = WH[f0],        bh10 = WH[f1];
    bf16x8 bh01 = WH[f0 + 64],   bh11 = WH[f1 + 64];
    bf16x8 bh02 = WH[f0 + 128],  bh12 = WH[f1 + 128];
    bf16x8 bh03 = WH[f0 + 192],  bh13 = WH[f1 + 192];
    asm volatile("" : "+v"(bh00), "+v"(bh01), "+v"(bh02), "+v"(bh03),
                      "+v"(bh10), "+v"(bh11), "+v"(bh12), "+v"(bh13));
    const float b2v0 = b2[dg * 16 + (l & 15)];
    const float b2v1 = b2[64 + dg * 16 + (l & 15)];
    const u16x8* xj8c = nullptr;           // set per round

    auto STAGE = [&](int u, int p) {
        const float4 va = *(const float4*)&v_s3[u][d0];
        const float4 vb = *(const float4*)&v_s3[u][d0 + 4];
        float v8[8];
        v8[0] = va.x; v8[1] = va.y; v8[2] = va.z; v8[3] = va.w;
        v8[4] = vb.x; v8[5] = vb.y; v8[6] = vb.z; v8[7] = vb.w;
#pragma unroll
        for (int it = 0; it < 3; ++it) {
            const int idx8 = t + it * 512;
            const int j = idx8 >> 4;
            const u16x8 xv = xj8c[idx8];
            u16x8 hh;
#pragma unroll
            for (int e = 0; e < 8; ++e)
                hh[e] = f2bf(fmaxf(bf2f(xv[e]) + v8[e], 0.f));
            *(u16x8*)&hs[p][(j * DD + d0) ^ ((j & 7) << 3)] = hh;
        }
    };

    auto GEMM = [&](int u, int p) {
        float aggp0 = 0.f, aggp1 = 0.f;
        const unsigned short* hb = hs[p];
#pragma unroll
        for (int jj = 0; jj < 3; ++jj) {
            const int jt  = jg3 + jj;
            const int r16 = jt * 16 + (l & 15);
            const int ko  = (l >> 4) * 8;
            const int sw  = (r16 & 7) << 3;
            const bf16x8 a0 = *(const bf16x8*)&hb[(r16 * DD + ko     ) ^ sw];
            const bf16x8 a1 = *(const bf16x8*)&hb[(r16 * DD + ko + 32) ^ sw];
            const bf16x8 a2 = *(const bf16x8*)&hb[(r16 * DD + ko + 64) ^ sw];
            const bf16x8 a3 = *(const bf16x8*)&hb[(r16 * DD + ko + 96) ^ sw];
            f32x4 c0 = {0.f, 0.f, 0.f, 0.f}, c1 = {0.f, 0.f, 0.f, 0.f};
            c0 = MFMA(a0, bh00, c0);  c1 = MFMA(a0, bh10, c1);
            c0 = MFMA(a1, bh01, c0);  c1 = MFMA(a1, bh11, c1);
            c0 = MFMA(a2, bh02, c0);  c1 = MFMA(a2, bh12, c1);
            c0 = MFMA(a3, bh03, c0);  c1 = MFMA(a3, bh13, c1);
#pragma unroll
            for (int r = 0; r < 4; ++r) {
                const float a = ac3_s[u][jt * 16 + (l >> 4) * 4 + r];
                aggp0 = fmaf(a, fmaxf(c0[r] + b2v0, 0.f), aggp0);
                aggp1 = fmaf(a, fmaxf(c1[r] + b2v1, 0.f), aggp1);
            }
        }
        aggp0 += __shfl_xor(aggp0, 16); aggp0 += __shfl_xor(aggp0, 32);
        aggp1 += __shfl_xor(aggp1, 16); aggp1 += __shfl_xor(aggp1, 32);
        if (l < 16) {
            agg_part[u][jg][dg * 16 + l]      = aggp0;
            agg_part[u][jg][64 + dg * 16 + l] = aggp1;
        }
    };

    // ---- 5 rounds ----
#pragma unroll 1
    for (int r = 0; r < 5; ++r) {
        const unsigned short* xin = (r & 1) ? xjB : xjA;
        unsigned short*       xot = (r & 1) ? xjA : xjB;
        xj8c = (const u16x8*)(xin + b * NN * DD);

        STAGE(0, 0);
        __syncthreads();
        STAGE(1, 1);
        GEMM(0, 0);
        __syncthreads();
        STAGE(2, 0);
        GEMM(1, 1);
        __syncthreads();
        GEMM(2, 0);
        __syncthreads();

        // P1: x update (register) + share
        if (w < 6) {
            xr += agg_part[u6][0][tt] + agg_part[u6][1][tt];
            xn_s[u6][tt] = xr;
        }
        __syncthreads();

        // P2: hid partials (Wo1 read once, 3 rows)
        {
            const int q = t >> 7, h = t & 127;
            float p0 = 0.f, p1 = 0.f, p2 = 0.f;
#pragma unroll
            for (int kk = 0; kk < 32; ++kk) {
                const int k = q * 32 + kk;
                const float wv = Wo1[k * DD + h];
                p0 = fmaf(xn_s[0][k], wv, p0);
                p1 = fmaf(xn_s[1][k], wv, p1);
                p2 = fmaf(xn_s[2][k], wv, p2);
            }
            part_s[q][0][h] = p0; part_s[q][1][h] = p1; part_s[q][2][h] = p2;
        }
        __syncthreads();

        // P3: hid + logits (wave-pair per row, 64-lane butterfly)
        if (w < 6) {
            const float hid = fmaxf(part_s[0][u6][tt] + part_s[1][u6][tt]
                                  + part_s[2][u6][tt] + part_s[3][u6][tt] + bo1[tt], 0.f);
            float lgp[NCLS];
#pragma unroll
            for (int c = 0; c < NCLS; ++c) lgp[c] = hid * Wo2[tt * NCLS + c];
#pragma unroll
            for (int s = 1; s < 64; s <<= 1) {
#pragma unroll
                for (int c = 0; c < NCLS; ++c) lgp[c] += __shfl_xor(lgp[c], s);
            }
            if (l == 0) {
#pragma unroll
                for (int c = 0; c < NCLS; ++c) wred[w & 1][u6][c] = lgp[c];
            }
        }
        __syncthreads();

        if (r == 4) {   // final: head -> out/x_all, done
            if (w < 6 && (w & 1) == 0 && l < NCLS) {
                const float lg = wred[0][u6][l] + wred[1][u6][l];
                x_all[(b * NN + is + 32 * u6) * NCLS + l] = lg;
                if (is == 0 && u6 == 0) out[b * NCLS + l] = lg;
            }
            break;
        }

        // P4: softmax + discretize (updates register x)
        if (w < 6) {
            float lg[NCLS];
            float mx = -1e30f;
#pragma unroll
            for (int c = 0; c < NCLS; ++c) {
                lg[c] = wred[0][u6][c] + wred[1][u6][c];
                mx = fmaxf(mx, lg[c]);
            }
            const float inv_tau = 1.f / scalar_as_float(tau_p[0]);
            float p[NCLS], den = 0.f;
#pragma unroll
            for (int c = 0; c < NCLS; ++c) { p[c] = expf((lg[c] - mx) * inv_tau); den += p[c]; }
            const float invden = 1.f / den;
#pragma unroll
            for (int c = 0; c < NCLS; ++c)
                xr = fmaf(p[c] * invden, embed_W[(4 + c) * DD + tt], xr);
            xn_s[u6][tt] = xr;
        }
        __syncthreads();

        // P5: next-round xj partials (W1x read once, 3 rows)
        {
            const int q = t >> 7, h = t & 127;
            float p0 = 0.f, p1 = 0.f, p2 = 0.f;
#pragma unroll
            for (int kk = 0; kk < 32; ++kk) {
                const int k = q * 32 + kk;
                const float wv = W1x[k * DD + h];
                p0 = fmaf(xn_s[0][k], wv, p0);
                p1 = fmaf(xn_s[1][k], wv, p1);
                p2 = fmaf(xn_s[2][k], wv, p2);
            }
            part_s[q][0][h] = p0; part_s[q][1][h] = p1; part_s[q][2][h] = p2;
        }
        __syncthreads();

        // P6: store xj bf16
        if (w < 6)
            xot[(b * NN + is + 32 * u6) * DD + tt] =
                f2bf(part_s[0][u6][tt] + part_s[1][u6][tt]
                   + part_s[2][u6][tt] + part_s[3][u6][tt]);

        gbar(cnt, 1 + r);   // xj visible to all blocks before next round
    }
}

extern "C" void kernel_launch(void* const* d_in, const int* in_sizes, int n_in,
                              void* d_out, int out_size, void* d_ws, size_t ws_size,
                              hipStream_t stream)
{
    (void)in_sizes; (void)n_in; (void)out_size; (void)ws_size;
    const int*   tok     = (const int*)d_in[0];
    const float* Aab     = (const float*)d_in[1];
    const float* embed_W = (const float*)d_in[2];
    const float* W1      = (const float*)d_in[3];
    const float* b1      = (const float*)d_in[4];
    const float* W2      = (const float*)d_in[5];
    const float* b2      = (const float*)d_in[6];
    const float* Wo1     = (const float*)d_in[7];
    const float* bo1     = (const float*)d_in[8];
    const float* Wo2     = (const float*)d_in[9];
    const int*   tau_p   = (const int*)d_in[11];

    float* out   = (float*)d_out;
    float* x_all = out + BB * NCLS;

    unsigned short* xjA  = (unsigned short*)d_ws;          // 196608 u16
    unsigned short* xjB  = xjA + BB * NN * DD;             // 196608 u16
    unsigned short* w2hi = xjB + BB * NN * DD;             // 16384 u16
    unsigned*       cnt  = (unsigned*)(w2hi + DD * DD);    // 8 slots

    hipMemsetAsync(cnt, 0, 8 * sizeof(unsigned), stream);
    k_all<<<NBLK, 512, 0, stream>>>(tok, Aab, embed_W, W1, b1, W2, b2,
                                    Wo1, bo1, Wo2, tau_p,
                                    w2hi, xjA, xjB, cnt, out, x_all);
}

// Round 12
// 84.674 us; speedup vs baseline: 9.8573x; 9.8573x over previous
//
#include <hip/hip_runtime.h>
#include <hip/hip_bf16.h>
#include <math.h>

#define BB   16
#define NN   96
#define DD   128
#define NCLS 10

typedef __attribute__((ext_vector_type(8))) short bf16x8;
typedef __attribute__((ext_vector_type(8))) unsigned short u16x8;
typedef __attribute__((ext_vector_type(4))) float f32x4;

__device__ __forceinline__ float scalar_as_float(int v) {
    if (v >= -1000000 && v <= 1000000) return (float)v;
    return __int_as_float(v);
}
__device__ __forceinline__ unsigned short f2bf(float f) {
    unsigned u = __float_as_uint(f);
    return (unsigned short)((u + 0x7FFFu + ((u >> 16) & 1u)) >> 16);
}
__device__ __forceinline__ float bf2f(unsigned short h) {
    return __uint_as_float(((unsigned)h) << 16);
}

#define MFMA(A, B, C) __builtin_amdgcn_mfma_f32_16x16x32_bf16(A, B, C, 0, 0, 0)

// ---- merged prep: init(384) | atrans(16) | w2 frag pack(8) | bf16 packs(8) ----
__global__ __launch_bounds__(256) void k_prep(
    const int* __restrict__ tok, const float* __restrict__ A,
    const float* __restrict__ embed_W, const float* __restrict__ W1,
    const float* __restrict__ W2, const float* __restrict__ Wo1,
    float* __restrict__ x, float* __restrict__ e_proj,
    unsigned short* __restrict__ xjA, float* __restrict__ AT,
    unsigned short* __restrict__ w2hi, unsigned short* __restrict__ w1xb,
    unsigned short* __restrict__ wo1b)
{
    const int bx = blockIdx.x;
    const int t  = threadIdx.x;
    const float* W1x = W1 + DD * DD;

    if (bx < 384) {          // init: 4 rows — x = e, e_proj = e@W1e, xjA = bf16(e@W1x)
        __shared__ float e_s[4][DD];
        const int rbase = bx * 4;
        const int rh = t >> 7, h = t & 127;   // thread owns rows rh*2, rh*2+1, feature h
        const int r0 = rh * 2, r1 = rh * 2 + 1;
        {
            const float e0 = embed_W[tok[rbase + r0] * DD + h];
            const float e1 = embed_W[tok[rbase + r1] * DD + h];
            e_s[r0][h] = e0;  x[(rbase + r0) * DD + h] = e0;
            e_s[r1][h] = e1;  x[(rbase + r1) * DD + h] = e1;
        }
        __syncthreads();
        float a10 = 0.f, a11 = 0.f, a20 = 0.f, a21 = 0.f;
#pragma unroll 8
        for (int k = 0; k < DD; ++k) {
            const float w1v  = W1[k * DD + h];
            const float w1xv = W1x[k * DD + h];
            a10 = fmaf(e_s[r0][k], w1v,  a10);
            a11 = fmaf(e_s[r1][k], w1v,  a11);
            a20 = fmaf(e_s[r0][k], w1xv, a20);
            a21 = fmaf(e_s[r1][k], w1xv, a21);
        }
        e_proj[(rbase + r0) * DD + h] = a10;
        e_proj[(rbase + r1) * DD + h] = a11;
        xjA[(rbase + r0) * DD + h] = f2bf(a20);
        xjA[(rbase + r1) * DD + h] = f2bf(a21);
    } else if (bx < 400) {   // A transpose: AT[b][i][j] = A[b][j][i]
        const int b = bx - 384;
        __shared__ float tile[NN][NN + 1];
        for (int idx = t; idx < NN * NN; idx += 256)
            tile[idx / NN][idx % NN] = A[b * NN * NN + idx];
        __syncthreads();
        for (int idx = t; idx < NN * NN; idx += 256) {
            const int i = idx / NN, j = idx % NN;
            AT[b * NN * NN + idx] = tile[j][i];
        }
    } else if (bx < 408) {   // W2 -> MFMA B-frag layout, bf16
        const int dt = bx - 400;
        const int kc = t >> 6, ll = t & 63;
        const int base = ((dt * 4 + kc) * 64 + ll) * 8;
        const int c = dt * 16 + (ll & 15);
#pragma unroll
        for (int e = 0; e < 8; ++e)
            w2hi[base + e] = f2bf(W2[(kc * 32 + (ll >> 4) * 8 + e) * DD + c]);
    } else if (bx < 412) {   // W1x -> bf16
        const int base = (bx - 408) * 4096 + t * 16;
#pragma unroll
        for (int e = 0; e < 16; ++e) w1xb[base + e] = f2bf(W1x[base + e]);
    } else {                 // Wo1 -> bf16 (used in DISC rounds only)
        const int base = (bx - 412) * 4096 + t * 16;
#pragma unroll
        for (int e = 0; e < 16; ++e) wo1b[base + e] = f2bf(Wo1[base + e]);
    }
}

// -------- per-round kernel: 3-unit pipelined GEMM + one-wave-per-row epilogue --------
// Grid = 512 = 16b x 32 i-slots = exactly 2 blocks/CU. Block owns rows {is, is+32, is+64}.
// Epilogue: wave u (u<3) owns row u, lane l owns features {l, l+64}; 64-lane butterfly
// gives FULL logits in-wave (wred LDS + 2 barriers eliminated vs R10).
// Wo1 bf16 in DISC rounds (discretize output bounded by O(1) centroids); fp32 for FIN.
template<int FIN>
__global__ __launch_bounds__(512, 4) void k_round(
    const float* __restrict__ AT, const float* __restrict__ e_proj,
    const unsigned short* __restrict__ xj_in, const float* __restrict__ b1,
    const unsigned short* __restrict__ w2hi, const float* __restrict__ b2,
    const float* __restrict__ Wo1, const unsigned short* __restrict__ wo1b,
    const float* __restrict__ bo1, const float* __restrict__ Wo2,
    const float* __restrict__ embed_W, const unsigned short* __restrict__ w1xb,
    const int* __restrict__ tau_p,
    float* __restrict__ x, unsigned short* __restrict__ xj_out,
    float* __restrict__ out, float* __restrict__ x_all)
{
    const int bx = blockIdx.x;   // 0..511
    const int b  = bx >> 5;      // batch 0..15
    const int is = bx & 31;      // rows is, is+32, is+64
    const int t  = threadIdx.x;  // 0..511
    const int w  = t >> 6;       // wave 0..7
    const int l  = t & 63;
    const int jg  = w >> 2;      // j-group 0..1 (3 j-tiles each)
    const int dg  = w & 3;       // d-group 0..3 (d-tiles dg, dg+4)
    const int jg3 = jg * 3;
    const int d0 = (t & 15) * 8; // STAGE d-slice
    const int row0 = b * NN + is;

    __shared__ __align__(16) unsigned short hs[2][NN * DD];  // 48 KB, XOR-swizzled
    __shared__ float ac_s[2][NN];
    __shared__ float agg_part[3][2][DD];   // [unit][jg][d]
    __shared__ float xn_s[3][DD];
    __shared__ float part_s[4][3][DD];     // [quarter][unit][h]

    // B-fragments: 2 d-tiles x 4 kc = 8 frags = 32 VGPR, pinned once
    const bf16x8* WH = (const bf16x8*)w2hi;
    const int f0 = (dg * 4) * 64 + l;
    const int f1 = ((dg + 4) * 4) * 64 + l;
    bf16x8 bh00 = WH[f0],        bh10 = WH[f1];
    bf16x8 bh01 = WH[f0 + 64],   bh11 = WH[f1 + 64];
    bf16x8 bh02 = WH[f0 + 128],  bh12 = WH[f1 + 128];
    bf16x8 bh03 = WH[f0 + 192],  bh13 = WH[f1 + 192];
    asm volatile("" : "+v"(bh00), "+v"(bh01), "+v"(bh02), "+v"(bh03),
                      "+v"(bh10), "+v"(bh11), "+v"(bh12), "+v"(bh13));
    const float b2v0 = b2[dg * 16 + (l & 15)];
    const float b2v1 = b2[64 + dg * 16 + (l & 15)];
    const float4 b4a = *(const float4*)(b1 + d0);
    const float4 b4b = *(const float4*)(b1 + d0 + 4);
    const u16x8* xj8 = (const u16x8*)(xj_in + b * NN * DD);

    auto STAGE = [&](int u, int p) {
        const int row_u = row0 + 32 * u;
        const float4 ea = *(const float4*)(e_proj + row_u * DD + d0);
        const float4 eb = *(const float4*)(e_proj + row_u * DD + d0 + 4);
        float v8[8];
        v8[0] = ea.x + b4a.x; v8[1] = ea.y + b4a.y;
        v8[2] = ea.z + b4a.z; v8[3] = ea.w + b4a.w;
        v8[4] = eb.x + b4b.x; v8[5] = eb.y + b4b.y;
        v8[6] = eb.z + b4b.z; v8[7] = eb.w + b4b.w;
        if (t < NN) ac_s[p][t] = AT[row_u * NN + t];
#pragma unroll
        for (int it = 0; it < 3; ++it) {
            const int idx8 = t + it * 512;     // (idx8&15)*8 == d0
            const int j = idx8 >> 4;
            const u16x8 xv = xj8[idx8];
            u16x8 hh;
#pragma unroll
            for (int e = 0; e < 8; ++e)
                hh[e] = f2bf(fmaxf(bf2f(xv[e]) + v8[e], 0.f));
            *(u16x8*)&hs[p][(j * DD + d0) ^ ((j & 7) << 3)] = hh;
        }
    };

    auto GEMM = [&](int u, int p) {
        float aggp0 = 0.f, aggp1 = 0.f;
        const unsigned short* hb = hs[p];
#pragma unroll
        for (int jj = 0; jj < 3; ++jj) {
            const int jt  = jg3 + jj;
            const int r16 = jt * 16 + (l & 15);
            const int ko  = (l >> 4) * 8;
            const int sw  = (r16 & 7) << 3;
            const bf16x8 a0 = *(const bf16x8*)&hb[(r16 * DD + ko     ) ^ sw];
            const bf16x8 a1 = *(const bf16x8*)&hb[(r16 * DD + ko + 32) ^ sw];
            const bf16x8 a2 = *(const bf16x8*)&hb[(r16 * DD + ko + 64) ^ sw];
            const bf16x8 a3 = *(const bf16x8*)&hb[(r16 * DD + ko + 96) ^ sw];
            f32x4 c0 = {0.f, 0.f, 0.f, 0.f}, c1 = {0.f, 0.f, 0.f, 0.f};
            c0 = MFMA(a0, bh00, c0);  c1 = MFMA(a0, bh10, c1);
            c0 = MFMA(a1, bh01, c0);  c1 = MFMA(a1, bh11, c1);
            c0 = MFMA(a2, bh02, c0);  c1 = MFMA(a2, bh12, c1);
            c0 = MFMA(a3, bh03, c0);  c1 = MFMA(a3, bh13, c1);
#pragma unroll
            for (int r = 0; r < 4; ++r) {
                const float a = ac_s[p][jt * 16 + (l >> 4) * 4 + r];
                aggp0 = fmaf(a, fmaxf(c0[r] + b2v0, 0.f), aggp0);
                aggp1 = fmaf(a, fmaxf(c1[r] + b2v1, 0.f), aggp1);
            }
        }
        aggp0 += __shfl_xor(aggp0, 16); aggp0 += __shfl_xor(aggp0, 32);
        aggp1 += __shfl_xor(aggp1, 16); aggp1 += __shfl_xor(aggp1, 32);
        if (l < 16) {
            agg_part[u][jg][dg * 16 + l]      = aggp0;
            agg_part[u][jg][64 + dg * 16 + l] = aggp1;
        }
    };

    // ---- pipelined main ----
    STAGE(0, 0);
    __syncthreads();
    STAGE(1, 1);
    GEMM(0, 0);
    __syncthreads();
    STAGE(2, 0);
    GEMM(1, 1);
    __syncthreads();
    GEMM(2, 0);
    __syncthreads();

    // ---- epilogue: wave u<3 owns row u, lane owns features {l, l+64} ----
    float xr0 = 0.f, xr1 = 0.f;
    if (w < 3) {
        const int row_u = row0 + 32 * w;
        xr0 = x[row_u * DD + l]      + agg_part[w][0][l]      + agg_part[w][1][l];
        xr1 = x[row_u * DD + l + 64] + agg_part[w][0][l + 64] + agg_part[w][1][l + 64];
        xn_s[w][l]      = xr0;
        xn_s[w][l + 64] = xr1;
    }
    __syncthreads();

    // hid partials: all waves; Wo1 fp32 for FIN (output path), bf16 for DISC
    {
        const int q = t >> 7, h = t & 127;
        float p0 = 0.f, p1 = 0.f, p2 = 0.f;
#pragma unroll
        for (int kk = 0; kk < 32; ++kk) {
            const int k = q * 32 + kk;
            const float wv = FIN ? Wo1[k * DD + h] : bf2f(wo1b[k * DD + h]);
            p0 = fmaf(xn_s[0][k], wv, p0);
            p1 = fmaf(xn_s[1][k], wv, p1);
            p2 = fmaf(xn_s[2][k], wv, p2);
        }
        part_s[q][0][h] = p0; part_s[q][1][h] = p1; part_s[q][2][h] = p2;
    }
    __syncthreads();

    // hid + logits (full in-wave butterfly) + [FIN store | softmax + x update]
    if (w < 3) {
        const int row_u = row0 + 32 * w;
        const float hid0 = fmaxf(part_s[0][w][l] + part_s[1][w][l]
                               + part_s[2][w][l] + part_s[3][w][l] + bo1[l], 0.f);
        const float hid1 = fmaxf(part_s[0][w][l + 64] + part_s[1][w][l + 64]
                               + part_s[2][w][l + 64] + part_s[3][w][l + 64] + bo1[l + 64], 0.f);
        float lgp[NCLS];
#pragma unroll
        for (int c = 0; c < NCLS; ++c)
            lgp[c] = hid0 * Wo2[l * NCLS + c] + hid1 * Wo2[(l + 64) * NCLS + c];
#pragma unroll
        for (int s = 1; s < 64; s <<= 1) {
#pragma unroll
            for (int c = 0; c < NCLS; ++c) lgp[c] += __shfl_xor(lgp[c], s);
        }
        if (FIN) {
#pragma unroll
            for (int c = 0; c < NCLS; ++c) {
                if (l == c) {
                    x_all[row_u * NCLS + c] = lgp[c];
                    if (is == 0 && w == 0) out[b * NCLS + c] = lgp[c];
                }
            }
        } else {
            float mx = -1e30f;
#pragma unroll
            for (int c = 0; c < NCLS; ++c) mx = fmaxf(mx, lgp[c]);
            const float inv_tau = 1.f / scalar_as_float(tau_p[0]);
            float p[NCLS], den = 0.f;
#pragma unroll
            for (int c = 0; c < NCLS; ++c) { p[c] = expf((lgp[c] - mx) * inv_tau); den += p[c]; }
            const float invden = 1.f / den;
#pragma unroll
            for (int c = 0; c < NCLS; ++c) {
                const float pc = p[c] * invden;
                xr0 = fmaf(pc, embed_W[(4 + c) * DD + l], xr0);
                xr1 = fmaf(pc, embed_W[(4 + c) * DD + l + 64], xr1);
            }
            x[row_u * DD + l]      = xr0;
            x[row_u * DD + l + 64] = xr1;
            xn_s[w][l]      = xr0;
            xn_s[w][l + 64] = xr1;
        }
    }
    if (FIN) return;
    __syncthreads();

    // next-round xj partials: W1x bf16 (xj is bf16-rounded anyway)
    {
        const int q = t >> 7, h = t & 127;
        float p0 = 0.f, p1 = 0.f, p2 = 0.f;
#pragma unroll
        for (int kk = 0; kk < 32; ++kk) {
            const int k = q * 32 + kk;
            const float wv = bf2f(w1xb[k * DD + h]);
            p0 = fmaf(xn_s[0][k], wv, p0);
            p1 = fmaf(xn_s[1][k], wv, p1);
            p2 = fmaf(xn_s[2][k], wv, p2);
        }
        part_s[q][0][h] = p0; part_s[q][1][h] = p1; part_s[q][2][h] = p2;
    }
    __syncthreads();

    if (w < 3) {
        const int row_u = row0 + 32 * w;
        xj_out[row_u * DD + l] =
            f2bf(part_s[0][w][l] + part_s[1][w][l] + part_s[2][w][l] + part_s[3][w][l]);
        xj_out[row_u * DD + l + 64] =
            f2bf(part_s[0][w][l + 64] + part_s[1][w][l + 64]
               + part_s[2][w][l + 64] + part_s[3][w][l + 64]);
    }
}

extern "C" void kernel_launch(void* const* d_in, const int* in_sizes, int n_in,
                              void* d_out, int out_size, void* d_ws, size_t ws_size,
                              hipStream_t stream)
{
    (void)in_sizes; (void)n_in; (void)out_size; (void)ws_size;
    const int*   tok     = (const int*)d_in[0];
    const float* Aab     = (const float*)d_in[1];
    const float* embed_W = (const float*)d_in[2];
    const float* W1      = (const float*)d_in[3];
    const float* b1      = (const float*)d_in[4];
    const float* W2      = (const float*)d_in[5];
    const float* b2      = (const float*)d_in[6];
    const float* Wo1     = (const float*)d_in[7];
    const float* bo1     = (const float*)d_in[8];
    const float* Wo2     = (const float*)d_in[9];
    const int*   tau_p   = (const int*)d_in[11];

    float* out   = (float*)d_out;
    float* x_all = out + BB * NCLS;

    float* ws     = (float*)d_ws;
    float* x      = ws;                                    // 196608 f
    float* e_proj = ws + BB * NN * DD;                     // 196608 f
    float* ATr    = ws + 2 * BB * NN * DD;                 // 147456 f
    unsigned short* xjA  = (unsigned short*)(ws + 2 * BB * NN * DD + BB * NN * NN);
    unsigned short* xjB  = xjA + BB * NN * DD;             // 196608 u16 each
    unsigned short* w2hi = xjB + BB * NN * DD;             // 16384 u16
    unsigned short* w1xb = w2hi + DD * DD;                 // 16384 u16
    unsigned short* wo1b = w1xb + DD * DD;                 // 16384 u16

    k_prep<<<416, 256, 0, stream>>>(tok, Aab, embed_W, W1, W2, Wo1,
                                    x, e_proj, xjA, ATr, w2hi, w1xb, wo1b);
    for (int r = 0; r < 5; ++r) {
        const unsigned short* xin = (r & 1) ? xjB : xjA;
        unsigned short*       xot = (r & 1) ? xjA : xjB;
        if (r < 4)
            k_round<0><<<512, 512, 0, stream>>>(ATr, e_proj, xin, b1, w2hi, b2,
                                                Wo1, wo1b, bo1, Wo2, embed_W, w1xb,
                                                tau_p, x, xot, out, x_all);
        else
            k_round<1><<<512, 512, 0, stream>>>(ATr, e_proj, xin, b1, w2hi, b2,
                                                Wo1, wo1b, bo1, Wo2, embed_W, w1xb,
                                                tau_p, x, xot, out, x_all);
    }
}

// Round 13
// 79.028 us; speedup vs baseline: 10.5616x; 1.0714x over previous
//
#include <hip/hip_runtime.h>
#include <hip/hip_bf16.h>
#include <math.h>

#define BB   16
#define NN   96
#define DD   128
#define NCLS 10
#define NTOK 14

typedef __attribute__((ext_vector_type(8))) short bf16x8;
typedef __attribute__((ext_vector_type(8))) unsigned short u16x8;
typedef __attribute__((ext_vector_type(4))) float f32x4;

__device__ __forceinline__ float scalar_as_float(int v) {
    if (v >= -1000000 && v <= 1000000) return (float)v;
    return __int_as_float(v);
}
__device__ __forceinline__ unsigned short f2bf(float f) {
    unsigned u = __float_as_uint(f);
    return (unsigned short)((u + 0x7FFFu + ((u >> 16) & 1u)) >> 16);
}
__device__ __forceinline__ float bf2f(unsigned short h) {
    return __uint_as_float(((unsigned)h) << 16);
}

#define MFMA(A, B, C) __builtin_amdgcn_mfma_f32_16x16x32_bf16(A, B, C, 0, 0, 0)

// ---- merged prep ----
// roles: [0,196) Mtab (ti,tj): M~=relu(relu(T2[ti]+b1+T1[tj])@W2 + b2), + t2tab when tj==0
//        [196,212) A transpose | [212,220) W2 frag pack | [220,224) W1x bf16 | [224,228) Wo1 bf16
__global__ __launch_bounds__(256) void k_prep(
    const float* __restrict__ A, const float* __restrict__ embed_W,
    const float* __restrict__ W1, const float* __restrict__ b1,
    const float* __restrict__ W2, const float* __restrict__ b2,
    const float* __restrict__ Wo1,
    float* __restrict__ Mtab, float* __restrict__ t2tab, float* __restrict__ AT,
    unsigned short* __restrict__ w2hi, unsigned short* __restrict__ w1xb,
    unsigned short* __restrict__ wo1b)
{
    const int bx = blockIdx.x;
    const int t  = threadIdx.x;
    const float* W1x = W1 + DD * DD;

    if (bx < NTOK * NTOK) {        // Mtab(ti,tj): only 196 distinct H rows exist in round 0
        const int ti = bx / NTOK, tj = bx % NTOK;
        const int d = t & 127, half = t >> 7;
        __shared__ float part[2][DD];
        __shared__ unsigned short hb[DD];
        {   // half0: T2row = e[ti]@W1e ; half1: T1row = e[tj]@W1x
            const float* erow  = embed_W + (half ? tj : ti) * DD;
            const float* wbase = half ? W1x : W1;
            float acc = 0.f;
#pragma unroll 8
            for (int k = 0; k < DD; ++k)
                acc = fmaf(erow[k], wbase[k * DD + d], acc);
            part[half][d] = acc;
        }
        __syncthreads();
        if (half == 0) {
            const float v = part[0][d] + b1[d];
            if (tj == 0) t2tab[ti * DD + d] = v;           // v = T2+b1 for k_round STAGE
            hb[d] = f2bf(fmaxf(v + part[1][d], 0.f));      // H row, bf16 (matches GEMM path)
        }
        __syncthreads();
        {   // M~ = relu(H @ bf16(W2) + b2), fp32 acc, k split in halves
            float m = 0.f;
#pragma unroll 8
            for (int kk = 0; kk < 64; ++kk) {
                const int k = half * 64 + kk;
                m = fmaf(bf2f(hb[k]), bf2f(f2bf(W2[k * DD + d])), m);
            }
            part[half][d] = m;
        }
        __syncthreads();
        if (half == 0)
            Mtab[(ti * NTOK + tj) * DD + d] = fmaxf(part[0][d] + part[1][d] + b2[d], 0.f);
    } else if (bx < 212) {         // A transpose
        const int b = bx - 196;
        __shared__ float tile[NN][NN + 1];
        for (int idx = t; idx < NN * NN; idx += 256)
            tile[idx / NN][idx % NN] = A[b * NN * NN + idx];
        __syncthreads();
        for (int idx = t; idx < NN * NN; idx += 256) {
            const int i = idx / NN, j = idx % NN;
            AT[b * NN * NN + idx] = tile[j][i];
        }
    } else if (bx < 220) {         // W2 -> MFMA B-frag layout, bf16
        const int dt = bx - 212;
        const int kc = t >> 6, ll = t & 63;
        const int base = ((dt * 4 + kc) * 64 + ll) * 8;
        const int c = dt * 16 + (ll & 15);
#pragma unroll
        for (int e = 0; e < 8; ++e)
            w2hi[base + e] = f2bf(W2[(kc * 32 + (ll >> 4) * 8 + e) * DD + c]);
    } else if (bx < 224) {         // W1x -> bf16
        const int base = (bx - 220) * 4096 + t * 16;
#pragma unroll
        for (int e = 0; e < 16; ++e) w1xb[base + e] = f2bf(W1x[base + e]);
    } else {                       // Wo1 -> bf16 (DISC rounds only)
        const int base = (bx - 224) * 4096 + t * 16;
#pragma unroll
        for (int e = 0; e < 16; ++e) wo1b[base + e] = f2bf(Wo1[base + e]);
    }
}

// -------- round 0 fast path: agg = A-weighted gather-sum over Mtab (no GEMM) --------
__global__ __launch_bounds__(512, 4) void k_round0(
    const int* __restrict__ tok, const float* __restrict__ AT,
    const float* __restrict__ Mtab, const float* __restrict__ embed_W,
    const unsigned short* __restrict__ wo1b, const float* __restrict__ bo1,
    const float* __restrict__ Wo2, const unsigned short* __restrict__ w1xb,
    const int* __restrict__ tau_p,
    float* __restrict__ x, unsigned short* __restrict__ xj_out)
{
    const int bx = blockIdx.x;
    const int b  = bx >> 5;
    const int is = bx & 31;
    const int t  = threadIdx.x;
    const int w  = t >> 6;
    const int l  = t & 63;
    const int row0 = b * NN + is;

    __shared__ __align__(16) float mt[3][NTOK * DD];   // 21 KB: M~ rows for the 3 ti's
    __shared__ float at3[3][NN];
    __shared__ int   tkj[NN];
    __shared__ float agg_s[3][DD];
    __shared__ float xn_s[3][DD];
    __shared__ float part_s[4][3][DD];

    const int ti0 = tok[row0], ti1 = tok[row0 + 32], ti2 = tok[row0 + 64];
    if (t < NN) {
        tkj[t]    = tok[b * NN + t];
        at3[0][t] = AT[row0 * NN + t];
        at3[1][t] = AT[(row0 + 32) * NN + t];
        at3[2][t] = AT[(row0 + 64) * NN + t];
    }
    for (int idx = t; idx < 3 * NTOK * DD; idx += 512) {
        const int u = idx / (NTOK * DD), rd = idx - u * (NTOK * DD);
        const int tiu = (u == 0) ? ti0 : ((u == 1) ? ti1 : ti2);
        mt[u][rd] = Mtab[tiu * NTOK * DD + rd];
    }
    __syncthreads();

    // agg[u][d] = sum_j A^T[row_u][j] * M~[ti_u][tok_j][d]; 192 threads, float2
    if (t < 192) {
        const int u = t >> 6, d2 = t & 63;
        const float2* mtu = (const float2*)mt[u];
        float2 acc = {0.f, 0.f};
#pragma unroll 4
        for (int j = 0; j < NN; ++j) {
            const float a = at3[u][j];
            const float2 m = mtu[tkj[j] * 64 + d2];
            acc.x = fmaf(a, m.x, acc.x);
            acc.y = fmaf(a, m.y, acc.y);
        }
        *(float2*)&agg_s[u][d2 * 2] = acc;
    }
    __syncthreads();

    // ---- DISC epilogue; x initialized from embed gather (x = e at round 0) ----
    float xr0 = 0.f, xr1 = 0.f;
    if (w < 3) {
        const int tk = (w == 0) ? ti0 : ((w == 1) ? ti1 : ti2);
        xr0 = embed_W[tk * DD + l]      + agg_s[w][l];
        xr1 = embed_W[tk * DD + l + 64] + agg_s[w][l + 64];
        xn_s[w][l]      = xr0;
        xn_s[w][l + 64] = xr1;
    }
    __syncthreads();

    {   // hid partials, Wo1 bf16
        const int q = t >> 7, h = t & 127;
        float p0 = 0.f, p1 = 0.f, p2 = 0.f;
#pragma unroll
        for (int kk = 0; kk < 32; ++kk) {
            const int k = q * 32 + kk;
            const float wv = bf2f(wo1b[k * DD + h]);
            p0 = fmaf(xn_s[0][k], wv, p0);
            p1 = fmaf(xn_s[1][k], wv, p1);
            p2 = fmaf(xn_s[2][k], wv, p2);
        }
        part_s[q][0][h] = p0; part_s[q][1][h] = p1; part_s[q][2][h] = p2;
    }
    __syncthreads();

    if (w < 3) {
        const int row_u = row0 + 32 * w;
        const float hid0 = fmaxf(part_s[0][w][l] + part_s[1][w][l]
                               + part_s[2][w][l] + part_s[3][w][l] + bo1[l], 0.f);
        const float hid1 = fmaxf(part_s[0][w][l + 64] + part_s[1][w][l + 64]
                               + part_s[2][w][l + 64] + part_s[3][w][l + 64] + bo1[l + 64], 0.f);
        float lgp[NCLS];
#pragma unroll
        for (int c = 0; c < NCLS; ++c)
            lgp[c] = hid0 * Wo2[l * NCLS + c] + hid1 * Wo2[(l + 64) * NCLS + c];
#pragma unroll
        for (int s = 1; s < 64; s <<= 1) {
#pragma unroll
            for (int c = 0; c < NCLS; ++c) lgp[c] += __shfl_xor(lgp[c], s);
        }
        float mx = -1e30f;
#pragma unroll
        for (int c = 0; c < NCLS; ++c) mx = fmaxf(mx, lgp[c]);
        const float inv_tau = 1.f / scalar_as_float(tau_p[0]);
        float p[NCLS], den = 0.f;
#pragma unroll
        for (int c = 0; c < NCLS; ++c) { p[c] = expf((lgp[c] - mx) * inv_tau); den += p[c]; }
        const float invden = 1.f / den;
#pragma unroll
        for (int c = 0; c < NCLS; ++c) {
            const float pc = p[c] * invden;
            xr0 = fmaf(pc, embed_W[(4 + c) * DD + l], xr0);
            xr1 = fmaf(pc, embed_W[(4 + c) * DD + l + 64], xr1);
        }
        x[row_u * DD + l]      = xr0;
        x[row_u * DD + l + 64] = xr1;
        xn_s[w][l]      = xr0;
        xn_s[w][l + 64] = xr1;
    }
    __syncthreads();

    {   // next-round xj partials (W1x bf16)
        const int q = t >> 7, h = t & 127;
        float p0 = 0.f, p1 = 0.f, p2 = 0.f;
#pragma unroll
        for (int kk = 0; kk < 32; ++kk) {
            const int k = q * 32 + kk;
            const float wv = bf2f(w1xb[k * DD + h]);
            p0 = fmaf(xn_s[0][k], wv, p0);
            p1 = fmaf(xn_s[1][k], wv, p1);
            p2 = fmaf(xn_s[2][k], wv, p2);
        }
        part_s[q][0][h] = p0; part_s[q][1][h] = p1; part_s[q][2][h] = p2;
    }
    __syncthreads();

    if (w < 3) {
        const int row_u = row0 + 32 * w;
        xj_out[row_u * DD + l] =
            f2bf(part_s[0][w][l] + part_s[1][w][l] + part_s[2][w][l] + part_s[3][w][l]);
        xj_out[row_u * DD + l + 64] =
            f2bf(part_s[0][w][l + 64] + part_s[1][w][l + 64]
               + part_s[2][w][l + 64] + part_s[3][w][l + 64]);
    }
}

// -------- rounds 1..4: 3-unit pipelined MFMA GEMM + one-wave-per-row epilogue --------
// STAGE v comes from t2tab[tok[row]] (b1 pre-folded) — e_proj buffer eliminated.
template<int FIN>
__global__ __launch_bounds__(512, 4) void k_round(
    const int* __restrict__ tok, const float* __restrict__ AT,
    const float* __restrict__ t2tab,
    const unsigned short* __restrict__ xj_in,
    const unsigned short* __restrict__ w2hi, const float* __restrict__ b2,
    const float* __restrict__ Wo1, const unsigned short* __restrict__ wo1b,
    const float* __restrict__ bo1, const float* __restrict__ Wo2,
    const float* __restrict__ embed_W, const unsigned short* __restrict__ w1xb,
    const int* __restrict__ tau_p,
    float* __restrict__ x, unsigned short* __restrict__ xj_out,
    float* __restrict__ out, float* __restrict__ x_all)
{
    const int bx = blockIdx.x;   // 0..511
    const int b  = bx >> 5;
    const int is = bx & 31;
    const int t  = threadIdx.x;  // 0..511
    const int w  = t >> 6;
    const int l  = t & 63;
    const int jg  = w >> 2;
    const int dg  = w & 3;
    const int jg3 = jg * 3;
    const int d0 = (t & 15) * 8;
    const int row0 = b * NN + is;

    __shared__ __align__(16) unsigned short hs[2][NN * DD];  // 48 KB, XOR-swizzled
    __shared__ float ac_s[2][NN];
    __shared__ float agg_part[3][2][DD];
    __shared__ float xn_s[3][DD];
    __shared__ float part_s[4][3][DD];

    const int tk0 = tok[row0], tk1 = tok[row0 + 32], tk2 = tok[row0 + 64];

    // B-fragments pinned once
    const bf16x8* WH = (const bf16x8*)w2hi;
    const int f0 = (dg * 4) * 64 + l;
    const int f1 = ((dg + 4) * 4) * 64 + l;
    bf16x8 bh00 = WH[f0],        bh10 = WH[f1];
    bf16x8 bh01 = WH[f0 + 64],   bh11 = WH[f1 + 64];
    bf16x8 bh02 = WH[f0 + 128],  bh12 = WH[f1 + 128];
    bf16x8 bh03 = WH[f0 + 192],  bh13 = WH[f1 + 192];
    asm volatile("" : "+v"(bh00), "+v"(bh01), "+v"(bh02), "+v"(bh03),
                      "+v"(bh10), "+v"(bh11), "+v"(bh12), "+v"(bh13));
    const float b2v0 = b2[dg * 16 + (l & 15)];
    const float b2v1 = b2[64 + dg * 16 + (l & 15)];
    const u16x8* xj8 = (const u16x8*)(xj_in + b * NN * DD);

    auto STAGE = [&](int u, int p) {
        const int row_u = row0 + 32 * u;
        const int tk = (u == 0) ? tk0 : ((u == 1) ? tk1 : tk2);
        const float4 ea = *(const float4*)(t2tab + tk * DD + d0);
        const float4 eb = *(const float4*)(t2tab + tk * DD + d0 + 4);
        float v8[8];
        v8[0] = ea.x; v8[1] = ea.y; v8[2] = ea.z; v8[3] = ea.w;
        v8[4] = eb.x; v8[5] = eb.y; v8[6] = eb.z; v8[7] = eb.w;
        if (t < NN) ac_s[p][t] = AT[row_u * NN + t];
#pragma unroll
        for (int it = 0; it < 3; ++it) {
            const int idx8 = t + it * 512;
            const int j = idx8 >> 4;
            const u16x8 xv = xj8[idx8];
            u16x8 hh;
#pragma unroll
            for (int e = 0; e < 8; ++e)
                hh[e] = f2bf(fmaxf(bf2f(xv[e]) + v8[e], 0.f));
            *(u16x8*)&hs[p][(j * DD + d0) ^ ((j & 7) << 3)] = hh;
        }
    };

    auto GEMM = [&](int u, int p) {
        float aggp0 = 0.f, aggp1 = 0.f;
        const unsigned short* hb = hs[p];
#pragma unroll
        for (int jj = 0; jj < 3; ++jj) {
            const int jt  = jg3 + jj;
            const int r16 = jt * 16 + (l & 15);
            const int ko  = (l >> 4) * 8;
            const int sw  = (r16 & 7) << 3;
            const bf16x8 a0 = *(const bf16x8*)&hb[(r16 * DD + ko     ) ^ sw];
            const bf16x8 a1 = *(const bf16x8*)&hb[(r16 * DD + ko + 32) ^ sw];
            const bf16x8 a2 = *(const bf16x8*)&hb[(r16 * DD + ko + 64) ^ sw];
            const bf16x8 a3 = *(const bf16x8*)&hb[(r16 * DD + ko + 96) ^ sw];
            f32x4 c0 = {0.f, 0.f, 0.f, 0.f}, c1 = {0.f, 0.f, 0.f, 0.f};
            c0 = MFMA(a0, bh00, c0);  c1 = MFMA(a0, bh10, c1);
            c0 = MFMA(a1, bh01, c0);  c1 = MFMA(a1, bh11, c1);
            c0 = MFMA(a2, bh02, c0);  c1 = MFMA(a2, bh12, c1);
            c0 = MFMA(a3, bh03, c0);  c1 = MFMA(a3, bh13, c1);
#pragma unroll
            for (int r = 0; r < 4; ++r) {
                const float a = ac_s[p][jt * 16 + (l >> 4) * 4 + r];
                aggp0 = fmaf(a, fmaxf(c0[r] + b2v0, 0.f), aggp0);
                aggp1 = fmaf(a, fmaxf(c1[r] + b2v1, 0.f), aggp1);
            }
        }
        aggp0 += __shfl_xor(aggp0, 16); aggp0 += __shfl_xor(aggp0, 32);
        aggp1 += __shfl_xor(aggp1, 16); aggp1 += __shfl_xor(aggp1, 32);
        if (l < 16) {
            agg_part[u][jg][dg * 16 + l]      = aggp0;
            agg_part[u][jg][64 + dg * 16 + l] = aggp1;
        }
    };

    STAGE(0, 0);
    __syncthreads();
    STAGE(1, 1);
    GEMM(0, 0);
    __syncthreads();
    STAGE(2, 0);
    GEMM(1, 1);
    __syncthreads();
    GEMM(2, 0);
    __syncthreads();

    // ---- epilogue: wave u<3 owns row u, lane owns features {l, l+64} ----
    float xr0 = 0.f, xr1 = 0.f;
    if (w < 3) {
        const int row_u = row0 + 32 * w;
        xr0 = x[row_u * DD + l]      + agg_part[w][0][l]      + agg_part[w][1][l];
        xr1 = x[row_u * DD + l + 64] + agg_part[w][0][l + 64] + agg_part[w][1][l + 64];
        xn_s[w][l]      = xr0;
        xn_s[w][l + 64] = xr1;
    }
    __syncthreads();

    {   // hid partials: Wo1 fp32 for FIN, bf16 for DISC
        const int q = t >> 7, h = t & 127;
        float p0 = 0.f, p1 = 0.f, p2 = 0.f;
#pragma unroll
        for (int kk = 0; kk < 32; ++kk) {
            const int k = q * 32 + kk;
            const float wv = FIN ? Wo1[k * DD + h] : bf2f(wo1b[k * DD + h]);
            p0 = fmaf(xn_s[0][k], wv, p0);
            p1 = fmaf(xn_s[1][k], wv, p1);
            p2 = fmaf(xn_s[2][k], wv, p2);
        }
        part_s[q][0][h] = p0; part_s[q][1][h] = p1; part_s[q][2][h] = p2;
    }
    __syncthreads();

    if (w < 3) {
        const int row_u = row0 + 32 * w;
        const float hid0 = fmaxf(part_s[0][w][l] + part_s[1][w][l]
                               + part_s[2][w][l] + part_s[3][w][l] + bo1[l], 0.f);
        const float hid1 = fmaxf(part_s[0][w][l + 64] + part_s[1][w][l + 64]
                               + part_s[2][w][l + 64] + part_s[3][w][l + 64] + bo1[l + 64], 0.f);
        float lgp[NCLS];
#pragma unroll
        for (int c = 0; c < NCLS; ++c)
            lgp[c] = hid0 * Wo2[l * NCLS + c] + hid1 * Wo2[(l + 64) * NCLS + c];
#pragma unroll
        for (int s = 1; s < 64; s <<= 1) {
#pragma unroll
            for (int c = 0; c < NCLS; ++c) lgp[c] += __shfl_xor(lgp[c], s);
        }
        if (FIN) {
#pragma unroll
            for (int c = 0; c < NCLS; ++c) {
                if (l == c) {
                    x_all[row_u * NCLS + c] = lgp[c];
                    if (is == 0 && w == 0) out[b * NCLS + c] = lgp[c];
                }
            }
        } else {
            float mx = -1e30f;
#pragma unroll
            for (int c = 0; c < NCLS; ++c) mx = fmaxf(mx, lgp[c]);
            const float inv_tau = 1.f / scalar_as_float(tau_p[0]);
            float p[NCLS], den = 0.f;
#pragma unroll
            for (int c = 0; c < NCLS; ++c) { p[c] = expf((lgp[c] - mx) * inv_tau); den += p[c]; }
            const float invden = 1.f / den;
#pragma unroll
            for (int c = 0; c < NCLS; ++c) {
                const float pc = p[c] * invden;
                xr0 = fmaf(pc, embed_W[(4 + c) * DD + l], xr0);
                xr1 = fmaf(pc, embed_W[(4 + c) * DD + l + 64], xr1);
            }
            x[row_u * DD + l]      = xr0;
            x[row_u * DD + l + 64] = xr1;
            xn_s[w][l]      = xr0;
            xn_s[w][l + 64] = xr1;
        }
    }
    if (FIN) return;
    __syncthreads();

    {   // next-round xj partials (W1x bf16)
        const int q = t >> 7, h = t & 127;
        float p0 = 0.f, p1 = 0.f, p2 = 0.f;
#pragma unroll
        for (int kk = 0; kk < 32; ++kk) {
            const int k = q * 32 + kk;
            const float wv = bf2f(w1xb[k * DD + h]);
            p0 = fmaf(xn_s[0][k], wv, p0);
            p1 = fmaf(xn_s[1][k], wv, p1);
            p2 = fmaf(xn_s[2][k], wv, p2);
        }
        part_s[q][0][h] = p0; part_s[q][1][h] = p1; part_s[q][2][h] = p2;
    }
    __syncthreads();

    if (w < 3) {
        const int row_u = row0 + 32 * w;
        xj_out[row_u * DD + l] =
            f2bf(part_s[0][w][l] + part_s[1][w][l] + part_s[2][w][l] + part_s[3][w][l]);
        xj_out[row_u * DD + l + 64] =
            f2bf(part_s[0][w][l + 64] + part_s[1][w][l + 64]
               + part_s[2][w][l + 64] + part_s[3][w][l + 64]);
    }
}

extern "C" void kernel_launch(void* const* d_in, const int* in_sizes, int n_in,
                              void* d_out, int out_size, void* d_ws, size_t ws_size,
                              hipStream_t stream)
{
    (void)in_sizes; (void)n_in; (void)out_size; (void)ws_size;
    const int*   tok     = (const int*)d_in[0];
    const float* Aab     = (const float*)d_in[1];
    const float* embed_W = (const float*)d_in[2];
    const float* W1      = (const float*)d_in[3];
    const float* b1      = (const float*)d_in[4];
    const float* W2      = (const float*)d_in[5];
    const float* b2      = (const float*)d_in[6];
    const float* Wo1     = (const float*)d_in[7];
    const float* bo1     = (const float*)d_in[8];
    const float* Wo2     = (const float*)d_in[9];
    const int*   tau_p   = (const int*)d_in[11];

    float* out   = (float*)d_out;
    float* x_all = out + BB * NCLS;

    float* ws     = (float*)d_ws;
    float* x      = ws;                                    // 196608 f
    float* ATr    = ws + BB * NN * DD;                     // 147456 f
    float* Mtab   = ATr + BB * NN * NN;                    // 25088 f
    float* t2tab  = Mtab + NTOK * NTOK * DD;               // 1792 f
    unsigned short* xjA  = (unsigned short*)(t2tab + NTOK * DD);
    unsigned short* xjB  = xjA + BB * NN * DD;             // 196608 u16 each
    unsigned short* w2hi = xjB + BB * NN * DD;             // 16384 u16
    unsigned short* w1xb = w2hi + DD * DD;                 // 16384 u16
    unsigned short* wo1b = w1xb + DD * DD;                 // 16384 u16

    k_prep<<<228, 256, 0, stream>>>(Aab, embed_W, W1, b1, W2, b2, Wo1,
                                    Mtab, t2tab, ATr, w2hi, w1xb, wo1b);
    k_round0<<<512, 512, 0, stream>>>(tok, ATr, Mtab, embed_W, wo1b, bo1,
                                      Wo2, w1xb, tau_p, x, xjA);
    for (int r = 1; r < 5; ++r) {
        const unsigned short* xin = (r & 1) ? xjA : xjB;
        unsigned short*       xot = (r & 1) ? xjB : xjA;
        if (r < 4)
            k_round<0><<<512, 512, 0, stream>>>(tok, ATr, t2tab, xin, w2hi, b2,
                                                Wo1, wo1b, bo1, Wo2, embed_W, w1xb,
                                                tau_p, x, xot, out, x_all);
        else
            k_round<1><<<512, 512, 0, stream>>>(tok, ATr, t2tab, xin, w2hi, b2,
                                                Wo1, wo1b, bo1, Wo2, embed_W, w1xb,
                                                tau_p, x, xot, out, x_all);
    }
}